// Round 6
// baseline (3220.059 us; speedup 1.0000x reference)
//
#include <hip/hip_runtime.h>
#include <hip/hip_bf16.h>
#include <math.h>

#define BATCH 2048
#define L 168
#define NTOT (BATCH*L)

typedef unsigned short ushort_t;
typedef unsigned int uint_t;
typedef __attribute__((ext_vector_type(8))) short bhalf8;
typedef __attribute__((ext_vector_type(4))) float f32x4;

// ---- ws layout ----
// float idx [0..1] sum,sumsq ; [16..2320) mask ; [2320..2832) bias0p
#define WS_MASK_F 16
#define WS_B0P_F 2320
#define OFF_W0P 12288                      // bytes; 7*512*32*2 = 229376
#define OFF_W1P (OFF_W0P + 7*512*32*2)     // 241664; 16*384*32*2 = 393216
#define OFF_W2P (OFF_W1P + 16*384*32*2)    // 634880; 12*256*32*2 = 196608

// ---- LDS: one 49152-B union region (feat [48][256]u16 s=512B / h0 [48][512]u16 s=1024B /
// h1 [48][384]u16 s=768B, all XOR-swizzled ^((row&7)<<4)) + xns ----
#define OFF_XN 49152
#define LDS_TOTAL (OFF_XN + 672)

__device__ __forceinline__ ushort_t f2bf(float v) {
    union { float f; unsigned int u; } q; q.f = v;
    unsigned int u = q.u;
    u += 0x7FFFu + ((u >> 16) & 1u);
    return (ushort_t)(u >> 16);
}

__device__ __forceinline__ uint_t pack_bf16(float a, float b) {
    float2 t; t.x = a; t.y = b;
    __hip_bfloat162 h2 = __float22bfloat162_rn(t);
    uint_t u; __builtin_memcpy(&u, &h2, 4);
    return u;
}

__global__ __launch_bounds__(256) void stats_kernel(const float* __restrict__ x, float* ws) {
    __shared__ float s_sum[256], s_sq[256];
    int tid = threadIdx.x;
    int idx = blockIdx.x * 256 + tid;
    float sum = 0.f, sq = 0.f;
    const float4* x4 = (const float4*)x;
    for (int i = idx; i < NTOT / 4; i += gridDim.x * 256) {
        float4 v = x4[i];
        sum += v.x + v.y + v.z + v.w;
        sq  += v.x*v.x + v.y*v.y + v.z*v.z + v.w*v.w;
    }
    s_sum[tid] = sum; s_sq[tid] = sq;
    __syncthreads();
    for (int s = 128; s > 0; s >>= 1) {
        if (tid < s) { s_sum[tid] += s_sum[tid+s]; s_sq[tid] += s_sq[tid+s]; }
        __syncthreads();
    }
    if (tid == 0) { atomicAdd(&ws[0], s_sum[0]); atomicAdd(&ws[1], s_sq[0]); }
}

__global__ __launch_bounds__(256) void mask_kernel(const float* __restrict__ wm, float* __restrict__ ws) {
    __shared__ float sv[256];
    int g = blockIdx.x, t = threadIdx.x;
    float v = (t < 144) ? wm[g*144 + t] : -INFINITY;
    sv[t] = v;
    __syncthreads();
    for (int s = 128; s > 0; s >>= 1) { if (t < s) sv[t] = fmaxf(sv[t], sv[t+s]); __syncthreads(); }
    float mx = sv[0];
    __syncthreads();
    float e = (t < 144) ? expf(v - mx) : 0.f;
    sv[t] = e;
    __syncthreads();
    for (int s = 128; s > 0; s >>= 1) { if (t < s) sv[t] += sv[t+s]; __syncthreads(); }
    if (t < 144) ws[WS_MASK_F + g*144 + t] = e / sv[0];
}

// Transformed weight prep (K=224 for L0: 196 pair-ch + 14 Q + 14 P), K-tile-major [kt][o][32].
__global__ __launch_bounds__(256) void prep_bf16(const float* __restrict__ w0, const float* __restrict__ b0,
                                                 const float* __restrict__ w1, const float* __restrict__ w2,
                                                 float* __restrict__ ws,
                                                 ushort_t* __restrict__ w0p, ushort_t* __restrict__ w1p,
                                                 ushort_t* __restrict__ w2p) {
    int idx = blockIdx.x * 256 + threadIdx.x;
    int stride = gridDim.x * 256;
    for (int i = idx; i < 7*16384; i += stride) {        // 512*32 per kt
        int kk = i & 31, o = (i >> 5) & 511, kt = i >> 14;
        int ch = kt*32 + kk;
        float v;
        if (ch < 196) {
            v = w0[o*588 + ch*3 + 1] + 0.5f * w0[o*588 + ch*3 + 2];
        } else if (ch < 210) {
            int n2 = ch - 196; float s = 0.f;
            for (int n1 = 0; n1 < 14; ++n1) s += w0[o*588 + (n1*14 + n2)*3];
            v = s;
        } else {
            int n1 = ch - 210; float s = 0.f;
            for (int n2 = 0; n2 < 14; ++n2) s += w0[o*588 + (n1*14 + n2)*3];
            v = -s;
        }
        w0p[i] = f2bf(v);
    }
    for (int i = idx; i < 16*12288; i += stride) {       // 384*32
        int kk = i & 31; int t = i >> 5; int o = t % 384; int kt = t / 384;
        w1p[i] = f2bf(w1[o*512 + kt*32 + kk]);
    }
    for (int i = idx; i < 12*8192; i += stride) {        // 256*32
        int kk = i & 31, o = (i >> 5) & 255, kt = i >> 13;
        w2p[i] = f2bf(w2[o*384 + kt*32 + kk]);
    }
    if (idx < 512) {
        float acc = 0.f;
        const float* wr = w0 + idx*588 + 2;
        for (int pr = 0; pr < 196; ++pr) acc += wr[3*pr];
        ws[WS_B0P_F + idx] = b0[idx] + 0.5f * acc;
    }
}

// One block per batch; 3 sequential M-slices of 48 rows. 512 threads = 8 waves.
// __launch_bounds__(512, 4): 128-VGPR cap fits the live set (R5's (512,6) -> 85-reg cap
// -> total spill catastrophe: 8.7 GB scratch traffic, MfmaUtil 3.5%).
__global__ __launch_bounds__(512, 4) void fused_mfma(
    const float* __restrict__ x,
    const float* __restrict__ b1, const float* __restrict__ b2,
    const float* __restrict__ wsf,
    const ushort_t* __restrict__ w0p, const ushort_t* __restrict__ w1p,
    const ushort_t* __restrict__ w2p, float* __restrict__ out)
{
    __shared__ __align__(16) char smem[LDS_TOTAL];
    float* xns = (float*)(smem + OFF_XN);

    const int tid  = threadIdx.x;
    const int b    = blockIdx.x;
    const int lane = tid & 63;
    const int w    = tid >> 6;
    const int col  = lane & 15;
    const int r4   = lane >> 4;
    const int swzA = (col & 7) << 4;     // row&7 == col&7 for rows m*16+col

    // ---- stats + xn ----
    {
        float sum = wsf[0], sq = wsf[1];
        float mean = sum / (float)NTOT;
        float var  = (sq - sum * mean) / (float)(NTOT - 1);
        float istd = 1.0f / sqrtf(var);
        if (tid < 168) xns[tid] = (x[b*L + tid] - mean) * istd;
    }

    const int NT0 = w * 4;
    const int NT1 = w * 3;
    const int NT2 = w * 2;
    float pooled[2] = {0.f, 0.f};

    for (int mi = 0; mi < 3; ++mi) {
        __syncthreads();   // xns ready (mi=0) / h1 reads done (mi>0)

        // ---- gen feature slab: rows [mi*48, mi*48+48), 224 ch, packed u32 pairs ----
        #pragma unroll
        for (int j = 0; j < 11; ++j) {
            int idx = tid + 512*j;
            if (idx < 5376) {                       // 48 rows * 112 ch-pairs
                int r  = (idx * 18725) >> 21;       // idx/112
                int cp = idx - r*112;
                int c0 = cp*2;
                int grow = mi*48 + r;
                int h  = (grow * 171) >> 11;        // grow/12
                int wv = grow - h*12;
                float v0, v1;
                if (c0 < 196) {
                    int n1a = (c0 * 293) >> 12, n2a = c0 - 14*n1a;
                    int c1 = c0 + 1;
                    int n1b = (c1 * 293) >> 12, n2b = (c1) - 14*n1b;
                    float xi0 = xns[n1a*12 + h], xj0 = xns[n2a*12 + wv];
                    v0 = (xj0 - xi0) * __builtin_amdgcn_rcpf(xi0 + xj0 + 1e-5f);
                    float xi1 = xns[n1b*12 + h], xj1 = xns[n2b*12 + wv];
                    v1 = (xj1 - xi1) * __builtin_amdgcn_rcpf(xi1 + xj1 + 1e-5f);
                } else {
                    v0 = (c0 < 210) ? xns[(c0-196)*12 + wv] : xns[(c0-210)*12 + h];
                    int c1 = c0 + 1;
                    v1 = (c1 < 210) ? xns[(c1-196)*12 + wv] : xns[(c1-210)*12 + h];
                }
                *(uint_t*)(smem + ((r*512 + c0*2) ^ ((r & 7) << 4))) = pack_bf16(v0, v1);
            }
        }
        __syncthreads();   // feat ready

        // ================= Layer 0: K=224 (7 kt), no barriers in loop =================
        {
            f32x4 acc[3][4];
            #pragma unroll
            for (int m = 0; m < 3; ++m)
                #pragma unroll
                for (int nt = 0; nt < 4; ++nt) acc[m][nt] = (f32x4){0.f,0.f,0.f,0.f};

            bhalf8 BA[4], BB[4];
            #define LOADB0(dst, ktv) { _Pragma("unroll") \
                for (int nt = 0; nt < 4; ++nt) \
                    dst[nt] = *(const bhalf8*)(w0p + (ktv)*16384 + ((NT0+nt)*16+col)*32 + r4*8); }
            #define PHASE0(B, ktv) { _Pragma("unroll") \
                for (int m = 0; m < 3; ++m) { \
                    int row = m*16 + col; \
                    bhalf8 a = *(const bhalf8*)(smem + ((row*512 + (ktv)*64 + r4*16) ^ swzA)); \
                    _Pragma("unroll") \
                    for (int nt = 0; nt < 4; ++nt) \
                        acc[m][nt] = __builtin_amdgcn_mfma_f32_16x16x32_bf16(a, B[nt], acc[m][nt], 0, 0, 0); } }

            LOADB0(BA, 0);
            for (int ktb = 0; ktb < 3; ++ktb) {
                int kt = 2*ktb;
                LOADB0(BB, kt+1);
                PHASE0(BA, kt);
                LOADB0(BA, kt+2);        // kt+2 <= 6, always valid
                PHASE0(BB, kt+1);
            }
            PHASE0(BA, 6);
            __syncthreads();   // all feat reads done before h0 overwrite
            const float* bias0p = wsf + WS_B0P_F;
            float bb[4];
            #pragma unroll
            for (int nt = 0; nt < 4; ++nt) bb[nt] = bias0p[(NT0+nt)*16 + col];
            #pragma unroll
            for (int m = 0; m < 3; ++m)
                #pragma unroll
                for (int nt = 0; nt < 4; ++nt) {
                    int o = (NT0+nt)*16 + col;
                    #pragma unroll
                    for (int qp = 0; qp < 2; ++qp) {
                        float v0 = fmaxf(acc[m][nt][2*qp]   + bb[nt], 0.f);
                        float v1 = fmaxf(acc[m][nt][2*qp+1] + bb[nt], 0.f);
                        uint_t pk = pack_bf16(v0, v1);
                        int row0 = m*16 + r4*4 + 2*qp;
                        *(ushort_t*)(smem + ((row0*1024 + o*2) ^ ((row0 & 7) << 4))) = (ushort_t)pk;
                        int row1 = row0 + 1;
                        *(ushort_t*)(smem + ((row1*1024 + o*2) ^ ((row1 & 7) << 4))) = (ushort_t)(pk >> 16);
                    }
                }
        }
        __syncthreads();   // h0 ready

        // ================= Layer 1: 512 -> 384 (16 kt), no barriers in loop =================
        {
            f32x4 acc1[3][3];
            #pragma unroll
            for (int m = 0; m < 3; ++m)
                #pragma unroll
                for (int nt = 0; nt < 3; ++nt) acc1[m][nt] = (f32x4){0.f,0.f,0.f,0.f};

            bhalf8 BA[3], BB[3];
            #define LOADB1(dst, ktv) { _Pragma("unroll") \
                for (int nt = 0; nt < 3; ++nt) \
                    dst[nt] = *(const bhalf8*)(w1p + (ktv)*12288 + ((NT1+nt)*16+col)*32 + r4*8); }
            #define PHASE1(B, ktv) { _Pragma("unroll") \
                for (int m = 0; m < 3; ++m) { \
                    int row = m*16 + col; \
                    bhalf8 a = *(const bhalf8*)(smem + ((row*1024 + (ktv)*64 + r4*16) ^ swzA)); \
                    _Pragma("unroll") \
                    for (int nt = 0; nt < 3; ++nt) \
                        acc1[m][nt] = __builtin_amdgcn_mfma_f32_16x16x32_bf16(a, B[nt], acc1[m][nt], 0, 0, 0); } }

            LOADB1(BA, 0);
            for (int ktb = 0; ktb < 8; ++ktb) {
                int kt = 2*ktb;
                LOADB1(BB, kt+1);
                PHASE1(BA, kt);
                if (kt+2 < 16) LOADB1(BA, kt+2);
                PHASE1(BB, kt+1);
            }
            __syncthreads();   // all h0 reads done before h1 overwrite
            float bb[3];
            #pragma unroll
            for (int nt = 0; nt < 3; ++nt) bb[nt] = b1[(NT1+nt)*16 + col];
            #pragma unroll
            for (int m = 0; m < 3; ++m)
                #pragma unroll
                for (int nt = 0; nt < 3; ++nt) {
                    int o = (NT1+nt)*16 + col;
                    #pragma unroll
                    for (int qp = 0; qp < 2; ++qp) {
                        float v0 = fmaxf(acc1[m][nt][2*qp]   + bb[nt], 0.f);
                        float v1 = fmaxf(acc1[m][nt][2*qp+1] + bb[nt], 0.f);
                        uint_t pk = pack_bf16(v0, v1);
                        int row0 = m*16 + r4*4 + 2*qp;
                        *(ushort_t*)(smem + ((row0*768 + o*2) ^ ((row0 & 7) << 4))) = (ushort_t)pk;
                        int row1 = row0 + 1;
                        *(ushort_t*)(smem + ((row1*768 + o*2) ^ ((row1 & 7) << 4))) = (ushort_t)(pk >> 16);
                    }
                }
        }
        __syncthreads();   // h1 ready

        // ================= Layer 2: 384 -> 256 (12 kt) + pool accumulate =================
        {
            f32x4 acc2[3][2];
            #pragma unroll
            for (int m = 0; m < 3; ++m)
                #pragma unroll
                for (int nt = 0; nt < 2; ++nt) acc2[m][nt] = (f32x4){0.f,0.f,0.f,0.f};

            bhalf8 BA[2], BB[2];
            #define LOADB2(dst, ktv) { _Pragma("unroll") \
                for (int nt = 0; nt < 2; ++nt) \
                    dst[nt] = *(const bhalf8*)(w2p + (ktv)*8192 + ((NT2+nt)*16+col)*32 + r4*8); }
            #define PHASE2(B, ktv) { _Pragma("unroll") \
                for (int m = 0; m < 3; ++m) { \
                    int row = m*16 + col; \
                    bhalf8 a = *(const bhalf8*)(smem + ((row*768 + (ktv)*64 + r4*16) ^ swzA)); \
                    _Pragma("unroll") \
                    for (int nt = 0; nt < 2; ++nt) \
                        acc2[m][nt] = __builtin_amdgcn_mfma_f32_16x16x32_bf16(a, B[nt], acc2[m][nt], 0, 0, 0); } }

            LOADB2(BA, 0);
            for (int ktb = 0; ktb < 6; ++ktb) {
                int kt = 2*ktb;
                LOADB2(BB, kt+1);
                PHASE2(BA, kt);
                if (kt+2 < 12) LOADB2(BA, kt+2);
                PHASE2(BB, kt+1);
            }
            const float* maskG = wsf + WS_MASK_F;
            float bb[2];
            #pragma unroll
            for (int nt = 0; nt < 2; ++nt) bb[nt] = b2[(NT2+nt)*16 + col];
            #pragma unroll
            for (int nt = 0; nt < 2; ++nt) {
                int g = NT2 + nt;
                #pragma unroll
                for (int m = 0; m < 3; ++m) {
                    int p0 = mi*48 + m*16 + r4*4;
                    float4 mv = *(const float4*)(maskG + g*144 + p0);
                    pooled[nt] += mv.x * fmaxf(acc2[m][nt][0] + bb[nt], 0.f);
                    pooled[nt] += mv.y * fmaxf(acc2[m][nt][1] + bb[nt], 0.f);
                    pooled[nt] += mv.z * fmaxf(acc2[m][nt][2] + bb[nt], 0.f);
                    pooled[nt] += mv.w * fmaxf(acc2[m][nt][3] + bb[nt], 0.f);
                }
            }
        }
        // loop-top barrier covers h1-read-done before next gen
    }

    #pragma unroll
    for (int nt = 0; nt < 2; ++nt) {
        pooled[nt] += __shfl_xor(pooled[nt], 16);
        pooled[nt] += __shfl_xor(pooled[nt], 32);
        if (r4 == 0) out[b*256 + (NT2+nt)*16 + col] = fmaxf(pooled[nt], 0.f);
    }
}

extern "C" void kernel_launch(void* const* d_in, const int* in_sizes, int n_in,
                              void* d_out, int out_size, void* d_ws, size_t ws_size,
                              hipStream_t stream) {
    const float* x  = (const float*)d_in[0];
    const float* w0 = (const float*)d_in[1];
    const float* b0 = (const float*)d_in[2];
    const float* w1 = (const float*)d_in[3];
    const float* b1 = (const float*)d_in[4];
    const float* w2 = (const float*)d_in[5];
    const float* b2 = (const float*)d_in[6];
    const float* wm = (const float*)d_in[7];
    float* out = (float*)d_out;
    float* wsf = (float*)d_ws;
    ushort_t* w0p = (ushort_t*)((char*)d_ws + OFF_W0P);
    ushort_t* w1p = (ushort_t*)((char*)d_ws + OFF_W1P);
    ushort_t* w2p = (ushort_t*)((char*)d_ws + OFF_W2P);

    hipMemsetAsync(d_ws, 0, 8, stream);
    stats_kernel<<<256, 256, 0, stream>>>(x, wsf);
    prep_bf16<<<512, 256, 0, stream>>>(w0, b0, w1, w2, wsf, w0p, w1p, w2p);
    mask_kernel<<<16, 256, 0, stream>>>(wm, wsf);
    fused_mfma<<<2048, 512, 0, stream>>>(x, b1, b2, wsf, w0p, w1p, w2p, out);
}

// Round 8
// 3095.742 us; speedup vs baseline: 1.0402x; 1.0402x over previous
//
#include <hip/hip_runtime.h>
#include <hip/hip_bf16.h>
#include <math.h>

#define BATCH 2048
#define L 168
#define NTOT (BATCH*L)

typedef unsigned short ushort_t;
typedef unsigned int uint_t;
typedef __attribute__((ext_vector_type(8))) short bhalf8;
typedef __attribute__((ext_vector_type(4))) float f32x4;

// ---- ws layout ----
// float idx [0..1] sum,sumsq ; [16..2320) mask ; [2320..2832) bias0p
#define WS_MASK_F 16
#define WS_B0P_F 2320
#define OFF_W0P 12288                      // bytes; 7*512*32*2 = 229376
#define OFF_W1P (OFF_W0P + 7*512*32*2)     // 241664; 16*384*32*2 = 393216
#define OFF_W2P (OFF_W1P + 16*384*32*2)    // 634880; 12*256*32*2 = 196608

// ---- LDS: one 49152-B union region (feat [48][256]u16 s=512B / h0 [48][512]u16 s=1024B /
// h1 [48][384]u16 s=768B, all XOR-swizzled ^((row&7)<<4)) + xns ----
#define OFF_XN 49152
#define LDS_TOTAL (OFF_XN + 672)

__device__ __forceinline__ ushort_t f2bf(float v) {
    union { float f; unsigned int u; } q; q.f = v;
    unsigned int u = q.u;
    u += 0x7FFFu + ((u >> 16) & 1u);
    return (ushort_t)(u >> 16);
}

__device__ __forceinline__ uint_t pack_bf16(float a, float b) {
    float2 t; t.x = a; t.y = b;
    __hip_bfloat162 h2 = __float22bfloat162_rn(t);
    uint_t u; __builtin_memcpy(&u, &h2, 4);
    return u;
}

__global__ __launch_bounds__(256) void stats_kernel(const float* __restrict__ x, float* ws) {
    __shared__ float s_sum[256], s_sq[256];
    int tid = threadIdx.x;
    int idx = blockIdx.x * 256 + tid;
    float sum = 0.f, sq = 0.f;
    const float4* x4 = (const float4*)x;
    for (int i = idx; i < NTOT / 4; i += gridDim.x * 256) {
        float4 v = x4[i];
        sum += v.x + v.y + v.z + v.w;
        sq  += v.x*v.x + v.y*v.y + v.z*v.z + v.w*v.w;
    }
    s_sum[tid] = sum; s_sq[tid] = sq;
    __syncthreads();
    for (int s = 128; s > 0; s >>= 1) {
        if (tid < s) { s_sum[tid] += s_sum[tid+s]; s_sq[tid] += s_sq[tid+s]; }
        __syncthreads();
    }
    if (tid == 0) { atomicAdd(&ws[0], s_sum[0]); atomicAdd(&ws[1], s_sq[0]); }
}

__global__ __launch_bounds__(256) void mask_kernel(const float* __restrict__ wm, float* __restrict__ ws) {
    __shared__ float sv[256];
    int g = blockIdx.x, t = threadIdx.x;
    float v = (t < 144) ? wm[g*144 + t] : -INFINITY;
    sv[t] = v;
    __syncthreads();
    for (int s = 128; s > 0; s >>= 1) { if (t < s) sv[t] = fmaxf(sv[t], sv[t+s]); __syncthreads(); }
    float mx = sv[0];
    __syncthreads();
    float e = (t < 144) ? expf(v - mx) : 0.f;
    sv[t] = e;
    __syncthreads();
    for (int s = 128; s > 0; s >>= 1) { if (t < s) sv[t] += sv[t+s]; __syncthreads(); }
    if (t < 144) ws[WS_MASK_F + g*144 + t] = e / sv[0];
}

// Transformed weight prep (K=224 for L0: 196 pair-ch + 14 Q + 14 P), K-tile-major [kt][o][32].
__global__ __launch_bounds__(256) void prep_bf16(const float* __restrict__ w0, const float* __restrict__ b0,
                                                 const float* __restrict__ w1, const float* __restrict__ w2,
                                                 float* __restrict__ ws,
                                                 ushort_t* __restrict__ w0p, ushort_t* __restrict__ w1p,
                                                 ushort_t* __restrict__ w2p) {
    int idx = blockIdx.x * 256 + threadIdx.x;
    int stride = gridDim.x * 256;
    for (int i = idx; i < 7*16384; i += stride) {        // 512*32 per kt
        int kk = i & 31, o = (i >> 5) & 511, kt = i >> 14;
        int ch = kt*32 + kk;
        float v;
        if (ch < 196) {
            v = w0[o*588 + ch*3 + 1] + 0.5f * w0[o*588 + ch*3 + 2];
        } else if (ch < 210) {
            int n2 = ch - 196; float s = 0.f;
            for (int n1 = 0; n1 < 14; ++n1) s += w0[o*588 + (n1*14 + n2)*3];
            v = s;
        } else {
            int n1 = ch - 210; float s = 0.f;
            for (int n2 = 0; n2 < 14; ++n2) s += w0[o*588 + (n1*14 + n2)*3];
            v = -s;
        }
        w0p[i] = f2bf(v);
    }
    for (int i = idx; i < 16*12288; i += stride) {       // 384*32
        int kk = i & 31; int t = i >> 5; int o = t % 384; int kt = t / 384;
        w1p[i] = f2bf(w1[o*512 + kt*32 + kk]);
    }
    for (int i = idx; i < 12*8192; i += stride) {        // 256*32
        int kk = i & 31, o = (i >> 5) & 255, kt = i >> 13;
        w2p[i] = f2bf(w2[o*384 + kt*32 + kk]);
    }
    if (idx < 512) {
        float acc = 0.f;
        const float* wr = w0 + idx*588 + 2;
        for (int pr = 0; pr < 196; ++pr) acc += wr[3*pr];
        ws[WS_B0P_F + idx] = b0[idx] + 0.5f * acc;
    }
}

// One block per batch; 3 sequential M-slices of 48 rows. 512 threads = 8 waves.
// __launch_bounds__(512, 2): LLVM computes VGPR cap = 256/waves_per_eu, so "2" -> 128-reg
// cap >= the ~105-reg live set (no spill). Hardware gives 16 waves/CU at <=128 regs (m69),
// and LDS 2x49KB <= 160KB -> 2 blocks/CU. R5's (512,6)->40-reg cap and R6's (512,4)->64-reg
// cap both forced multi-GB scratch spill (MfmaUtil 3%).
__global__ __launch_bounds__(512, 2) void fused_mfma(
    const float* __restrict__ x,
    const float* __restrict__ b1, const float* __restrict__ b2,
    const float* __restrict__ wsf,
    const ushort_t* __restrict__ w0p, const ushort_t* __restrict__ w1p,
    const ushort_t* __restrict__ w2p, float* __restrict__ out)
{
    __shared__ __align__(16) char smem[LDS_TOTAL];
    float* xns = (float*)(smem + OFF_XN);

    const int tid  = threadIdx.x;
    const int b    = blockIdx.x;
    const int lane = tid & 63;
    const int w    = tid >> 6;
    const int col  = lane & 15;
    const int r4   = lane >> 4;
    const int swzA = (col & 7) << 4;     // row&7 == col&7 for rows m*16+col

    // ---- stats + xn ----
    {
        float sum = wsf[0], sq = wsf[1];
        float mean = sum / (float)NTOT;
        float var  = (sq - sum * mean) / (float)(NTOT - 1);
        float istd = 1.0f / sqrtf(var);
        if (tid < 168) xns[tid] = (x[b*L + tid] - mean) * istd;
    }

    const int NT0 = w * 4;
    const int NT1 = w * 3;
    const int NT2 = w * 2;
    float pooled[2] = {0.f, 0.f};

    for (int mi = 0; mi < 3; ++mi) {
        __syncthreads();   // xns ready (mi=0) / h1 reads done (mi>0)

        // ---- gen feature slab: rows [mi*48, mi*48+48), 224 ch, packed u32 pairs ----
        #pragma unroll
        for (int j = 0; j < 11; ++j) {
            int idx = tid + 512*j;
            if (idx < 5376) {                       // 48 rows * 112 ch-pairs
                int r  = (idx * 18725) >> 21;       // idx/112
                int cp = idx - r*112;
                int c0 = cp*2;
                int grow = mi*48 + r;
                int h  = (grow * 171) >> 11;        // grow/12
                int wv = grow - h*12;
                float v0, v1;
                if (c0 < 196) {
                    int n1a = (c0 * 293) >> 12, n2a = c0 - 14*n1a;
                    int c1 = c0 + 1;
                    int n1b = (c1 * 293) >> 12, n2b = (c1) - 14*n1b;
                    float xi0 = xns[n1a*12 + h], xj0 = xns[n2a*12 + wv];
                    v0 = (xj0 - xi0) * __builtin_amdgcn_rcpf(xi0 + xj0 + 1e-5f);
                    float xi1 = xns[n1b*12 + h], xj1 = xns[n2b*12 + wv];
                    v1 = (xj1 - xi1) * __builtin_amdgcn_rcpf(xi1 + xj1 + 1e-5f);
                } else {
                    v0 = (c0 < 210) ? xns[(c0-196)*12 + wv] : xns[(c0-210)*12 + h];
                    int c1 = c0 + 1;
                    v1 = (c1 < 210) ? xns[(c1-196)*12 + wv] : xns[(c1-210)*12 + h];
                }
                *(uint_t*)(smem + ((r*512 + c0*2) ^ ((r & 7) << 4))) = pack_bf16(v0, v1);
            }
        }
        __syncthreads();   // feat ready

        // ================= Layer 0: K=224 (7 kt), no barriers in loop =================
        {
            f32x4 acc[3][4];
            #pragma unroll
            for (int m = 0; m < 3; ++m)
                #pragma unroll
                for (int nt = 0; nt < 4; ++nt) acc[m][nt] = (f32x4){0.f,0.f,0.f,0.f};

            bhalf8 BA[4], BB[4];
            #define LOADB0(dst, ktv) { _Pragma("unroll") \
                for (int nt = 0; nt < 4; ++nt) \
                    dst[nt] = *(const bhalf8*)(w0p + (ktv)*16384 + ((NT0+nt)*16+col)*32 + r4*8); }
            #define PHASE0(B, ktv) { _Pragma("unroll") \
                for (int m = 0; m < 3; ++m) { \
                    int row = m*16 + col; \
                    bhalf8 a = *(const bhalf8*)(smem + ((row*512 + (ktv)*64 + r4*16) ^ swzA)); \
                    _Pragma("unroll") \
                    for (int nt = 0; nt < 4; ++nt) \
                        acc[m][nt] = __builtin_amdgcn_mfma_f32_16x16x32_bf16(a, B[nt], acc[m][nt], 0, 0, 0); } }

            LOADB0(BA, 0);
            for (int ktb = 0; ktb < 3; ++ktb) {
                int kt = 2*ktb;
                LOADB0(BB, kt+1);
                PHASE0(BA, kt);
                LOADB0(BA, kt+2);        // kt+2 <= 6, always valid
                PHASE0(BB, kt+1);
            }
            PHASE0(BA, 6);
            __syncthreads();   // all feat reads done before h0 overwrite
            const float* bias0p = wsf + WS_B0P_F;
            float bb[4];
            #pragma unroll
            for (int nt = 0; nt < 4; ++nt) bb[nt] = bias0p[(NT0+nt)*16 + col];
            #pragma unroll
            for (int m = 0; m < 3; ++m)
                #pragma unroll
                for (int nt = 0; nt < 4; ++nt) {
                    int o = (NT0+nt)*16 + col;
                    #pragma unroll
                    for (int qp = 0; qp < 2; ++qp) {
                        float v0 = fmaxf(acc[m][nt][2*qp]   + bb[nt], 0.f);
                        float v1 = fmaxf(acc[m][nt][2*qp+1] + bb[nt], 0.f);
                        uint_t pk = pack_bf16(v0, v1);
                        int row0 = m*16 + r4*4 + 2*qp;
                        *(ushort_t*)(smem + ((row0*1024 + o*2) ^ ((row0 & 7) << 4))) = (ushort_t)pk;
                        int row1 = row0 + 1;
                        *(ushort_t*)(smem + ((row1*1024 + o*2) ^ ((row1 & 7) << 4))) = (ushort_t)(pk >> 16);
                    }
                }
        }
        __syncthreads();   // h0 ready

        // ================= Layer 1: 512 -> 384 (16 kt), no barriers in loop =================
        {
            f32x4 acc1[3][3];
            #pragma unroll
            for (int m = 0; m < 3; ++m)
                #pragma unroll
                for (int nt = 0; nt < 3; ++nt) acc1[m][nt] = (f32x4){0.f,0.f,0.f,0.f};

            bhalf8 BA[3], BB[3];
            #define LOADB1(dst, ktv) { _Pragma("unroll") \
                for (int nt = 0; nt < 3; ++nt) \
                    dst[nt] = *(const bhalf8*)(w1p + (ktv)*12288 + ((NT1+nt)*16+col)*32 + r4*8); }
            #define PHASE1(B, ktv) { _Pragma("unroll") \
                for (int m = 0; m < 3; ++m) { \
                    int row = m*16 + col; \
                    bhalf8 a = *(const bhalf8*)(smem + ((row*1024 + (ktv)*64 + r4*16) ^ swzA)); \
                    _Pragma("unroll") \
                    for (int nt = 0; nt < 3; ++nt) \
                        acc1[m][nt] = __builtin_amdgcn_mfma_f32_16x16x32_bf16(a, B[nt], acc1[m][nt], 0, 0, 0); } }

            LOADB1(BA, 0);
            for (int ktb = 0; ktb < 8; ++ktb) {
                int kt = 2*ktb;
                LOADB1(BB, kt+1);
                PHASE1(BA, kt);
                if (kt+2 < 16) LOADB1(BA, kt+2);
                PHASE1(BB, kt+1);
            }
            __syncthreads();   // all h0 reads done before h1 overwrite
            float bb[3];
            #pragma unroll
            for (int nt = 0; nt < 3; ++nt) bb[nt] = b1[(NT1+nt)*16 + col];
            #pragma unroll
            for (int m = 0; m < 3; ++m)
                #pragma unroll
                for (int nt = 0; nt < 3; ++nt) {
                    int o = (NT1+nt)*16 + col;
                    #pragma unroll
                    for (int qp = 0; qp < 2; ++qp) {
                        float v0 = fmaxf(acc1[m][nt][2*qp]   + bb[nt], 0.f);
                        float v1 = fmaxf(acc1[m][nt][2*qp+1] + bb[nt], 0.f);
                        uint_t pk = pack_bf16(v0, v1);
                        int row0 = m*16 + r4*4 + 2*qp;
                        *(ushort_t*)(smem + ((row0*768 + o*2) ^ ((row0 & 7) << 4))) = (ushort_t)pk;
                        int row1 = row0 + 1;
                        *(ushort_t*)(smem + ((row1*768 + o*2) ^ ((row1 & 7) << 4))) = (ushort_t)(pk >> 16);
                    }
                }
        }
        __syncthreads();   // h1 ready

        // ================= Layer 2: 384 -> 256 (12 kt) + pool accumulate =================
        {
            f32x4 acc2[3][2];
            #pragma unroll
            for (int m = 0; m < 3; ++m)
                #pragma unroll
                for (int nt = 0; nt < 2; ++nt) acc2[m][nt] = (f32x4){0.f,0.f,0.f,0.f};

            bhalf8 BA[2], BB[2];
            #define LOADB2(dst, ktv) { _Pragma("unroll") \
                for (int nt = 0; nt < 2; ++nt) \
                    dst[nt] = *(const bhalf8*)(w2p + (ktv)*8192 + ((NT2+nt)*16+col)*32 + r4*8); }
            #define PHASE2(B, ktv) { _Pragma("unroll") \
                for (int m = 0; m < 3; ++m) { \
                    int row = m*16 + col; \
                    bhalf8 a = *(const bhalf8*)(smem + ((row*768 + (ktv)*64 + r4*16) ^ swzA)); \
                    _Pragma("unroll") \
                    for (int nt = 0; nt < 2; ++nt) \
                        acc2[m][nt] = __builtin_amdgcn_mfma_f32_16x16x32_bf16(a, B[nt], acc2[m][nt], 0, 0, 0); } }

            LOADB2(BA, 0);
            for (int ktb = 0; ktb < 6; ++ktb) {
                int kt = 2*ktb;
                LOADB2(BB, kt+1);
                PHASE2(BA, kt);
                if (kt+2 < 12) LOADB2(BA, kt+2);
                PHASE2(BB, kt+1);
            }
            const float* maskG = wsf + WS_MASK_F;
            float bb[2];
            #pragma unroll
            for (int nt = 0; nt < 2; ++nt) bb[nt] = b2[(NT2+nt)*16 + col];
            #pragma unroll
            for (int nt = 0; nt < 2; ++nt) {
                int g = NT2 + nt;
                #pragma unroll
                for (int m = 0; m < 3; ++m) {
                    int p0 = mi*48 + m*16 + r4*4;
                    float4 mv = *(const float4*)(maskG + g*144 + p0);
                    pooled[nt] += mv.x * fmaxf(acc2[m][nt][0] + bb[nt], 0.f);
                    pooled[nt] += mv.y * fmaxf(acc2[m][nt][1] + bb[nt], 0.f);
                    pooled[nt] += mv.z * fmaxf(acc2[m][nt][2] + bb[nt], 0.f);
                    pooled[nt] += mv.w * fmaxf(acc2[m][nt][3] + bb[nt], 0.f);
                }
            }
        }
        // loop-top barrier covers h1-read-done before next gen
    }

    #pragma unroll
    for (int nt = 0; nt < 2; ++nt) {
        pooled[nt] += __shfl_xor(pooled[nt], 16);
        pooled[nt] += __shfl_xor(pooled[nt], 32);
        if (r4 == 0) out[b*256 + (NT2+nt)*16 + col] = fmaxf(pooled[nt], 0.f);
    }
}

extern "C" void kernel_launch(void* const* d_in, const int* in_sizes, int n_in,
                              void* d_out, int out_size, void* d_ws, size_t ws_size,
                              hipStream_t stream) {
    const float* x  = (const float*)d_in[0];
    const float* w0 = (const float*)d_in[1];
    const float* b0 = (const float*)d_in[2];
    const float* w1 = (const float*)d_in[3];
    const float* b1 = (const float*)d_in[4];
    const float* w2 = (const float*)d_in[5];
    const float* b2 = (const float*)d_in[6];
    const float* wm = (const float*)d_in[7];
    float* out = (float*)d_out;
    float* wsf = (float*)d_ws;
    ushort_t* w0p = (ushort_t*)((char*)d_ws + OFF_W0P);
    ushort_t* w1p = (ushort_t*)((char*)d_ws + OFF_W1P);
    ushort_t* w2p = (ushort_t*)((char*)d_ws + OFF_W2P);

    hipMemsetAsync(d_ws, 0, 8, stream);
    stats_kernel<<<256, 256, 0, stream>>>(x, wsf);
    prep_bf16<<<512, 256, 0, stream>>>(w0, b0, w1, w2, wsf, w0p, w1p, w2p);
    mask_kernel<<<16, 256, 0, stream>>>(wm, wsf);
    fused_mfma<<<2048, 512, 0, stream>>>(x, b1, b2, wsf, w0p, w1p, w2p, out);
}

// Round 9
// 515.942 us; speedup vs baseline: 6.2411x; 6.0002x over previous
//
#include <hip/hip_runtime.h>
#include <hip/hip_bf16.h>
#include <math.h>

#define BATCH 2048
#define L 168
#define NTOT (BATCH*L)

typedef unsigned short ushort_t;
typedef unsigned int uint_t;
typedef __attribute__((ext_vector_type(8))) short bhalf8;
typedef __attribute__((ext_vector_type(4))) float f32x4;

// ---- ws layout ----
#define WS_MASK_F 16
#define WS_B0P_F 2320
#define OFF_W0P 12288                      // bytes; 7*512*32*2 = 229376
#define OFF_W1P (OFF_W0P + 7*512*32*2)     // 241664
#define OFF_W2P (OFF_W1P + 16*384*32*2)    // 634880

// ---- LDS: 49152-B union (feat [48][256]u16 s=512B / h0 [48][512]u16 s=1024B /
// h1 [48][384]u16 s=768B, all XOR-swizzled ^((row&7)<<4)) + xns ----
#define OFF_XN 49152
#define LDS_TOTAL (OFF_XN + 672)

__device__ __forceinline__ ushort_t f2bf(float v) {
    union { float f; unsigned int u; } q; q.f = v;
    unsigned int u = q.u;
    u += 0x7FFFu + ((u >> 16) & 1u);
    return (ushort_t)(u >> 16);
}

__device__ __forceinline__ uint_t pack_bf16(float a, float b) {
    float2 t; t.x = a; t.y = b;
    __hip_bfloat162 h2 = __float22bfloat162_rn(t);
    uint_t u; __builtin_memcpy(&u, &h2, 4);
    return u;
}

__global__ __launch_bounds__(256) void stats_kernel(const float* __restrict__ x, float* ws) {
    __shared__ float s_sum[256], s_sq[256];
    int tid = threadIdx.x;
    int idx = blockIdx.x * 256 + tid;
    float sum = 0.f, sq = 0.f;
    const float4* x4 = (const float4*)x;
    for (int i = idx; i < NTOT / 4; i += gridDim.x * 256) {
        float4 v = x4[i];
        sum += v.x + v.y + v.z + v.w;
        sq  += v.x*v.x + v.y*v.y + v.z*v.z + v.w*v.w;
    }
    s_sum[tid] = sum; s_sq[tid] = sq;
    __syncthreads();
    for (int s = 128; s > 0; s >>= 1) {
        if (tid < s) { s_sum[tid] += s_sum[tid+s]; s_sq[tid] += s_sq[tid+s]; }
        __syncthreads();
    }
    if (tid == 0) { atomicAdd(&ws[0], s_sum[0]); atomicAdd(&ws[1], s_sq[0]); }
}

__global__ __launch_bounds__(256) void mask_kernel(const float* __restrict__ wm, float* __restrict__ ws) {
    __shared__ float sv[256];
    int g = blockIdx.x, t = threadIdx.x;
    float v = (t < 144) ? wm[g*144 + t] : -INFINITY;
    sv[t] = v;
    __syncthreads();
    for (int s = 128; s > 0; s >>= 1) { if (t < s) sv[t] = fmaxf(sv[t], sv[t+s]); __syncthreads(); }
    float mx = sv[0];
    __syncthreads();
    float e = (t < 144) ? expf(v - mx) : 0.f;
    sv[t] = e;
    __syncthreads();
    for (int s = 128; s > 0; s >>= 1) { if (t < s) sv[t] += sv[t+s]; __syncthreads(); }
    if (t < 144) ws[WS_MASK_F + g*144 + t] = e / sv[0];
}

// Transformed weight prep (K=224 for L0: 196 pair-ch + 14 Q + 14 P), K-tile-major [kt][o][32].
__global__ __launch_bounds__(256) void prep_bf16(const float* __restrict__ w0, const float* __restrict__ b0,
                                                 const float* __restrict__ w1, const float* __restrict__ w2,
                                                 float* __restrict__ ws,
                                                 ushort_t* __restrict__ w0p, ushort_t* __restrict__ w1p,
                                                 ushort_t* __restrict__ w2p) {
    int idx = blockIdx.x * 256 + threadIdx.x;
    int stride = gridDim.x * 256;
    for (int i = idx; i < 7*16384; i += stride) {
        int kk = i & 31, o = (i >> 5) & 511, kt = i >> 14;
        int ch = kt*32 + kk;
        float v;
        if (ch < 196) {
            v = w0[o*588 + ch*3 + 1] + 0.5f * w0[o*588 + ch*3 + 2];
        } else if (ch < 210) {
            int n2 = ch - 196; float s = 0.f;
            for (int n1 = 0; n1 < 14; ++n1) s += w0[o*588 + (n1*14 + n2)*3];
            v = s;
        } else {
            int n1 = ch - 210; float s = 0.f;
            for (int n2 = 0; n2 < 14; ++n2) s += w0[o*588 + (n1*14 + n2)*3];
            v = -s;
        }
        w0p[i] = f2bf(v);
    }
    for (int i = idx; i < 16*12288; i += stride) {
        int kk = i & 31; int t = i >> 5; int o = t % 384; int kt = t / 384;
        w1p[i] = f2bf(w1[o*512 + kt*32 + kk]);
    }
    for (int i = idx; i < 12*8192; i += stride) {
        int kk = i & 31, o = (i >> 5) & 255, kt = i >> 13;
        w2p[i] = f2bf(w2[o*384 + kt*32 + kk]);
    }
    if (idx < 512) {
        float acc = 0.f;
        const float* wr = w0 + idx*588 + 2;
        for (int pr = 0; pr < 196; ++pr) acc += wr[3*pr];
        ws[WS_B0P_F + idx] = b0[idx] + 0.5f * acc;
    }
}

// ONE BLOCK PER (batch, M-slice): grid 3*2048, no outer loop (R5-R8's mi-loop drove
// intrinsic multi-GB scratch spill regardless of launch-bounds cap). Each block does
// gen -> L0 -> L1 -> L2 -> pool-partial once, then atomicAdd into out.
// Final relu(pooled) is a no-op: mask>=0, h>=0 => pooled>=0 => partials compose.
// (512,2): LLVM VGPR cap = 256/min_waves = 128 >= ~110-reg live set.
__global__ __launch_bounds__(512, 2) void fused_mfma(
    const float* __restrict__ x,
    const float* __restrict__ b1, const float* __restrict__ b2,
    const float* __restrict__ wsf,
    const ushort_t* __restrict__ w0p, const ushort_t* __restrict__ w1p,
    const ushort_t* __restrict__ w2p, float* __restrict__ out)
{
    __shared__ __align__(16) char smem[LDS_TOTAL];
    float* xns = (float*)(smem + OFF_XN);

    const int tid  = threadIdx.x;
    const int bid  = blockIdx.x;
    const int mi   = bid >> 11;          // 0..2
    const int b    = bid & 2047;
    const int lane = tid & 63;
    const int w    = tid >> 6;
    const int col  = lane & 15;
    const int r4   = lane >> 4;
    const int swzA = (col & 7) << 4;

    // ---- stats + xn ----
    {
        float sum = wsf[0], sq = wsf[1];
        float mean = sum / (float)NTOT;
        float var  = (sq - sum * mean) / (float)(NTOT - 1);
        float istd = 1.0f / sqrtf(var);
        if (tid < 168) xns[tid] = (x[b*L + tid] - mean) * istd;
    }
    __syncthreads();

    // ---- gen feature slab: rows [mi*48, mi*48+48), 224 ch, packed u32 pairs ----
    #pragma unroll
    for (int j = 0; j < 11; ++j) {
        int idx = tid + 512*j;
        if (idx < 5376) {                       // 48 rows * 112 ch-pairs
            int r  = (idx * 18725) >> 21;       // idx/112
            int cp = idx - r*112;
            int c0 = cp*2;
            int grow = mi*48 + r;
            int h  = (grow * 171) >> 11;        // grow/12
            int wv = grow - h*12;
            float v0, v1;
            if (c0 < 196) {
                int n1a = (c0 * 293) >> 12, n2a = c0 - 14*n1a;
                int c1 = c0 + 1;
                int n1b = (c1 * 293) >> 12, n2b = c1 - 14*n1b;
                float xi0 = xns[n1a*12 + h], xj0 = xns[n2a*12 + wv];
                v0 = (xj0 - xi0) * __builtin_amdgcn_rcpf(xi0 + xj0 + 1e-5f);
                float xi1 = xns[n1b*12 + h], xj1 = xns[n2b*12 + wv];
                v1 = (xj1 - xi1) * __builtin_amdgcn_rcpf(xi1 + xj1 + 1e-5f);
            } else {
                v0 = (c0 < 210) ? xns[(c0-196)*12 + wv] : xns[(c0-210)*12 + h];
                int c1 = c0 + 1;
                v1 = (c1 < 210) ? xns[(c1-196)*12 + wv] : xns[(c1-210)*12 + h];
            }
            *(uint_t*)(smem + ((r*512 + c0*2) ^ ((r & 7) << 4))) = pack_bf16(v0, v1);
        }
    }
    __syncthreads();   // feat ready

    const int NT0 = w * 4;
    const int NT1 = w * 3;
    const int NT2 = w * 2;

    // ================= Layer 0: K=224 (7 kt), no barriers in loop =================
    {
        f32x4 acc[3][4];
        #pragma unroll
        for (int m = 0; m < 3; ++m)
            #pragma unroll
            for (int nt = 0; nt < 4; ++nt) acc[m][nt] = (f32x4){0.f,0.f,0.f,0.f};

        bhalf8 BA[4], BB[4];
        #define LOADB0(dst, ktv) { _Pragma("unroll") \
            for (int nt = 0; nt < 4; ++nt) \
                dst[nt] = *(const bhalf8*)(w0p + (ktv)*16384 + ((NT0+nt)*16+col)*32 + r4*8); }
        #define PHASE0(B, ktv) { _Pragma("unroll") \
            for (int m = 0; m < 3; ++m) { \
                int row = m*16 + col; \
                bhalf8 a = *(const bhalf8*)(smem + ((row*512 + (ktv)*64 + r4*16) ^ swzA)); \
                _Pragma("unroll") \
                for (int nt = 0; nt < 4; ++nt) \
                    acc[m][nt] = __builtin_amdgcn_mfma_f32_16x16x32_bf16(a, B[nt], acc[m][nt], 0, 0, 0); } }

        LOADB0(BA, 0);
        for (int ktb = 0; ktb < 3; ++ktb) {
            int kt = 2*ktb;
            LOADB0(BB, kt+1);
            PHASE0(BA, kt);
            LOADB0(BA, kt+2);        // kt+2 <= 6, always valid
            PHASE0(BB, kt+1);
        }
        PHASE0(BA, 6);
        __syncthreads();   // all feat reads done before h0 overwrite
        const float* bias0p = wsf + WS_B0P_F;
        float bb[4];
        #pragma unroll
        for (int nt = 0; nt < 4; ++nt) bb[nt] = bias0p[(NT0+nt)*16 + col];
        #pragma unroll
        for (int m = 0; m < 3; ++m)
            #pragma unroll
            for (int nt = 0; nt < 4; ++nt) {
                int o = (NT0+nt)*16 + col;
                #pragma unroll
                for (int qp = 0; qp < 2; ++qp) {
                    float v0 = fmaxf(acc[m][nt][2*qp]   + bb[nt], 0.f);
                    float v1 = fmaxf(acc[m][nt][2*qp+1] + bb[nt], 0.f);
                    uint_t pk = pack_bf16(v0, v1);
                    int row0 = m*16 + r4*4 + 2*qp;
                    *(ushort_t*)(smem + ((row0*1024 + o*2) ^ ((row0 & 7) << 4))) = (ushort_t)pk;
                    int row1 = row0 + 1;
                    *(ushort_t*)(smem + ((row1*1024 + o*2) ^ ((row1 & 7) << 4))) = (ushort_t)(pk >> 16);
                }
            }
    }
    __syncthreads();   // h0 ready

    // ================= Layer 1: 512 -> 384 (16 kt), no barriers in loop =================
    {
        f32x4 acc1[3][3];
        #pragma unroll
        for (int m = 0; m < 3; ++m)
            #pragma unroll
            for (int nt = 0; nt < 3; ++nt) acc1[m][nt] = (f32x4){0.f,0.f,0.f,0.f};

        bhalf8 BA[3], BB[3];
        #define LOADB1(dst, ktv) { _Pragma("unroll") \
            for (int nt = 0; nt < 3; ++nt) \
                dst[nt] = *(const bhalf8*)(w1p + (ktv)*12288 + ((NT1+nt)*16+col)*32 + r4*8); }
        #define PHASE1(B, ktv) { _Pragma("unroll") \
            for (int m = 0; m < 3; ++m) { \
                int row = m*16 + col; \
                bhalf8 a = *(const bhalf8*)(smem + ((row*1024 + (ktv)*64 + r4*16) ^ swzA)); \
                _Pragma("unroll") \
                for (int nt = 0; nt < 3; ++nt) \
                    acc1[m][nt] = __builtin_amdgcn_mfma_f32_16x16x32_bf16(a, B[nt], acc1[m][nt], 0, 0, 0); } }

        LOADB1(BA, 0);
        for (int ktb = 0; ktb < 8; ++ktb) {
            int kt = 2*ktb;
            LOADB1(BB, kt+1);
            PHASE1(BA, kt);
            if (kt+2 < 16) LOADB1(BA, kt+2);
            PHASE1(BB, kt+1);
        }
        __syncthreads();   // all h0 reads done before h1 overwrite
        float bb[3];
        #pragma unroll
        for (int nt = 0; nt < 3; ++nt) bb[nt] = b1[(NT1+nt)*16 + col];
        #pragma unroll
        for (int m = 0; m < 3; ++m)
            #pragma unroll
            for (int nt = 0; nt < 3; ++nt) {
                int o = (NT1+nt)*16 + col;
                #pragma unroll
                for (int qp = 0; qp < 2; ++qp) {
                    float v0 = fmaxf(acc1[m][nt][2*qp]   + bb[nt], 0.f);
                    float v1 = fmaxf(acc1[m][nt][2*qp+1] + bb[nt], 0.f);
                    uint_t pk = pack_bf16(v0, v1);
                    int row0 = m*16 + r4*4 + 2*qp;
                    *(ushort_t*)(smem + ((row0*768 + o*2) ^ ((row0 & 7) << 4))) = (ushort_t)pk;
                    int row1 = row0 + 1;
                    *(ushort_t*)(smem + ((row1*768 + o*2) ^ ((row1 & 7) << 4))) = (ushort_t)(pk >> 16);
                }
            }
    }
    __syncthreads();   // h1 ready

    // ================= Layer 2: 384 -> 256 (12 kt) + pool partial =================
    {
        f32x4 acc2[3][2];
        #pragma unroll
        for (int m = 0; m < 3; ++m)
            #pragma unroll
            for (int nt = 0; nt < 2; ++nt) acc2[m][nt] = (f32x4){0.f,0.f,0.f,0.f};

        bhalf8 BA[2], BB[2];
        #define LOADB2(dst, ktv) { _Pragma("unroll") \
            for (int nt = 0; nt < 2; ++nt) \
                dst[nt] = *(const bhalf8*)(w2p + (ktv)*8192 + ((NT2+nt)*16+col)*32 + r4*8); }
        #define PHASE2(B, ktv) { _Pragma("unroll") \
            for (int m = 0; m < 3; ++m) { \
                int row = m*16 + col; \
                bhalf8 a = *(const bhalf8*)(smem + ((row*768 + (ktv)*64 + r4*16) ^ swzA)); \
                _Pragma("unroll") \
                for (int nt = 0; nt < 2; ++nt) \
                    acc2[m][nt] = __builtin_amdgcn_mfma_f32_16x16x32_bf16(a, B[nt], acc2[m][nt], 0, 0, 0); } }

        LOADB2(BA, 0);
        for (int ktb = 0; ktb < 6; ++ktb) {
            int kt = 2*ktb;
            LOADB2(BB, kt+1);
            PHASE2(BA, kt);
            if (kt+2 < 12) LOADB2(BA, kt+2);
            PHASE2(BB, kt+1);
        }
        const float* maskG = wsf + WS_MASK_F;
        float bb[2];
        #pragma unroll
        for (int nt = 0; nt < 2; ++nt) bb[nt] = b2[(NT2+nt)*16 + col];
        float pooled[2] = {0.f, 0.f};
        #pragma unroll
        for (int nt = 0; nt < 2; ++nt) {
            int g = NT2 + nt;
            #pragma unroll
            for (int m = 0; m < 3; ++m) {
                int p0 = mi*48 + m*16 + r4*4;
                float4 mv = *(const float4*)(maskG + g*144 + p0);
                pooled[nt] += mv.x * fmaxf(acc2[m][nt][0] + bb[nt], 0.f);
                pooled[nt] += mv.y * fmaxf(acc2[m][nt][1] + bb[nt], 0.f);
                pooled[nt] += mv.z * fmaxf(acc2[m][nt][2] + bb[nt], 0.f);
                pooled[nt] += mv.w * fmaxf(acc2[m][nt][3] + bb[nt], 0.f);
            }
        }
        #pragma unroll
        for (int nt = 0; nt < 2; ++nt) {
            pooled[nt] += __shfl_xor(pooled[nt], 16);
            pooled[nt] += __shfl_xor(pooled[nt], 32);
            if (r4 == 0) atomicAdd(&out[b*256 + (NT2+nt)*16 + col], pooled[nt]);
        }
    }
}

extern "C" void kernel_launch(void* const* d_in, const int* in_sizes, int n_in,
                              void* d_out, int out_size, void* d_ws, size_t ws_size,
                              hipStream_t stream) {
    const float* x  = (const float*)d_in[0];
    const float* w0 = (const float*)d_in[1];
    const float* b0 = (const float*)d_in[2];
    const float* w1 = (const float*)d_in[3];
    const float* b1 = (const float*)d_in[4];
    const float* w2 = (const float*)d_in[5];
    const float* b2 = (const float*)d_in[6];
    const float* wm = (const float*)d_in[7];
    float* out = (float*)d_out;
    float* wsf = (float*)d_ws;
    ushort_t* w0p = (ushort_t*)((char*)d_ws + OFF_W0P);
    ushort_t* w1p = (ushort_t*)((char*)d_ws + OFF_W1P);
    ushort_t* w2p = (ushort_t*)((char*)d_ws + OFF_W2P);

    hipMemsetAsync(d_ws, 0, 8, stream);
    hipMemsetAsync(d_out, 0, (size_t)out_size * sizeof(float), stream);
    stats_kernel<<<256, 256, 0, stream>>>(x, wsf);
    prep_bf16<<<512, 256, 0, stream>>>(w0, b0, w1, w2, wsf, w0p, w1p, w2p);
    mask_kernel<<<16, 256, 0, stream>>>(wm, wsf);
    fused_mfma<<<3*2048, 512, 0, stream>>>(x, b1, b2, wsf, w0p, w1p, w2p, out);
}

// Round 10
// 408.477 us; speedup vs baseline: 7.8831x; 1.2631x over previous
//
#include <hip/hip_runtime.h>
#include <hip/hip_bf16.h>
#include <math.h>

#define BATCH 2048
#define L 168
#define NTOT (BATCH*L)

typedef unsigned short ushort_t;
typedef unsigned int uint_t;
typedef __attribute__((ext_vector_type(8))) short bhalf8;
typedef __attribute__((ext_vector_type(4))) float f32x4;

// ---- ws layout ----
#define WS_MASK_F 16
#define WS_B0P_F 2320
#define OFF_W0P 12288                      // bytes; 7*512*32*2 = 229376
#define OFF_W1P (OFF_W0P + 7*512*32*2)     // 241664
#define OFF_W2P (OFF_W1P + 16*384*32*2)    // 634880

// ---- LDS regions (bytes) ----
// [0, 49152)       h0 [48][512]u16 s=1024B -> later h1 [48][384]u16 s=768B (XOR-swz)
// [49152, 73728)   feat [48][256]u16 s=512B (XOR-swz)  -- separate so L0 pass2 can re-read
// [73728, 74400)   xns[168] f32
// Total 74.4 KB -> 2 blocks/CU by LDS (148.8 <= 160 KB). Register target: arch+AGPR < 128
// so 4 waves/SIMD fit -> 2 blocks co-resident (R9: acc[3][4]=48 AGPR + 72 arch => 1 block).
#define OFF_FEAT 49152
#define OFF_XN 73728
#define LDS_TOTAL (OFF_XN + 672)

__device__ __forceinline__ ushort_t f2bf(float v) {
    union { float f; unsigned int u; } q; q.f = v;
    unsigned int u = q.u;
    u += 0x7FFFu + ((u >> 16) & 1u);
    return (ushort_t)(u >> 16);
}

__device__ __forceinline__ uint_t pack_bf16(float a, float b) {
    float2 t; t.x = a; t.y = b;
    __hip_bfloat162 h2 = __float22bfloat162_rn(t);
    uint_t u; __builtin_memcpy(&u, &h2, 4);
    return u;
}

__global__ __launch_bounds__(256) void stats_kernel(const float* __restrict__ x, float* ws) {
    __shared__ float s_sum[256], s_sq[256];
    int tid = threadIdx.x;
    int idx = blockIdx.x * 256 + tid;
    float sum = 0.f, sq = 0.f;
    const float4* x4 = (const float4*)x;
    for (int i = idx; i < NTOT / 4; i += gridDim.x * 256) {
        float4 v = x4[i];
        sum += v.x + v.y + v.z + v.w;
        sq  += v.x*v.x + v.y*v.y + v.z*v.z + v.w*v.w;
    }
    s_sum[tid] = sum; s_sq[tid] = sq;
    __syncthreads();
    for (int s = 128; s > 0; s >>= 1) {
        if (tid < s) { s_sum[tid] += s_sum[tid+s]; s_sq[tid] += s_sq[tid+s]; }
        __syncthreads();
    }
    if (tid == 0) { atomicAdd(&ws[0], s_sum[0]); atomicAdd(&ws[1], s_sq[0]); }
}

__global__ __launch_bounds__(256) void mask_kernel(const float* __restrict__ wm, float* __restrict__ ws) {
    __shared__ float sv[256];
    int g = blockIdx.x, t = threadIdx.x;
    float v = (t < 144) ? wm[g*144 + t] : -INFINITY;
    sv[t] = v;
    __syncthreads();
    for (int s = 128; s > 0; s >>= 1) { if (t < s) sv[t] = fmaxf(sv[t], sv[t+s]); __syncthreads(); }
    float mx = sv[0];
    __syncthreads();
    float e = (t < 144) ? expf(v - mx) : 0.f;
    sv[t] = e;
    __syncthreads();
    for (int s = 128; s > 0; s >>= 1) { if (t < s) sv[t] += sv[t+s]; __syncthreads(); }
    if (t < 144) ws[WS_MASK_F + g*144 + t] = e / sv[0];
}

// Transformed weight prep (K=224 for L0: 196 pair-ch + 14 Q + 14 P), K-tile-major [kt][o][32].
__global__ __launch_bounds__(256) void prep_bf16(const float* __restrict__ w0, const float* __restrict__ b0,
                                                 const float* __restrict__ w1, const float* __restrict__ w2,
                                                 float* __restrict__ ws,
                                                 ushort_t* __restrict__ w0p, ushort_t* __restrict__ w1p,
                                                 ushort_t* __restrict__ w2p) {
    int idx = blockIdx.x * 256 + threadIdx.x;
    int stride = gridDim.x * 256;
    for (int i = idx; i < 7*16384; i += stride) {
        int kk = i & 31, o = (i >> 5) & 511, kt = i >> 14;
        int ch = kt*32 + kk;
        float v;
        if (ch < 196) {
            v = w0[o*588 + ch*3 + 1] + 0.5f * w0[o*588 + ch*3 + 2];
        } else if (ch < 210) {
            int n2 = ch - 196; float s = 0.f;
            for (int n1 = 0; n1 < 14; ++n1) s += w0[o*588 + (n1*14 + n2)*3];
            v = s;
        } else {
            int n1 = ch - 210; float s = 0.f;
            for (int n2 = 0; n2 < 14; ++n2) s += w0[o*588 + (n1*14 + n2)*3];
            v = -s;
        }
        w0p[i] = f2bf(v);
    }
    for (int i = idx; i < 16*12288; i += stride) {
        int kk = i & 31; int t = i >> 5; int o = t % 384; int kt = t / 384;
        w1p[i] = f2bf(w1[o*512 + kt*32 + kk]);
    }
    for (int i = idx; i < 12*8192; i += stride) {
        int kk = i & 31, o = (i >> 5) & 255, kt = i >> 13;
        w2p[i] = f2bf(w2[o*384 + kt*32 + kk]);
    }
    if (idx < 512) {
        float acc = 0.f;
        const float* wr = w0 + idx*588 + 2;
        for (int pr = 0; pr < 196; ++pr) acc += wr[3*pr];
        ws[WS_B0P_F + idx] = b0[idx] + 0.5f * acc;
    }
}

// One block per (batch, M-slice): grid 3*2048. gen -> L0(2 nt-passes) -> L1 -> L2 -> atomic pool.
__global__ __launch_bounds__(512, 2) void fused_mfma(
    const float* __restrict__ x,
    const float* __restrict__ b1, const float* __restrict__ b2,
    const float* __restrict__ wsf,
    const ushort_t* __restrict__ w0p, const ushort_t* __restrict__ w1p,
    const ushort_t* __restrict__ w2p, float* __restrict__ out)
{
    __shared__ __align__(16) char smem[LDS_TOTAL];
    float* xns = (float*)(smem + OFF_XN);

    const int tid  = threadIdx.x;
    const int bid  = blockIdx.x;
    const int mi   = bid >> 11;          // 0..2
    const int b    = bid & 2047;
    const int lane = tid & 63;
    const int w    = tid >> 6;
    const int col  = lane & 15;
    const int r4   = lane >> 4;
    const int swzA = (col & 7) << 4;

    // ---- stats + xn ----
    {
        float sum = wsf[0], sq = wsf[1];
        float mean = sum / (float)NTOT;
        float var  = (sq - sum * mean) / (float)(NTOT - 1);
        float istd = 1.0f / sqrtf(var);
        if (tid < 168) xns[tid] = (x[b*L + tid] - mean) * istd;
    }
    __syncthreads();

    // ---- gen feature slab: rows [mi*48, mi*48+48), 224 ch, packed u32 pairs ----
    #pragma unroll
    for (int j = 0; j < 11; ++j) {
        int idx = tid + 512*j;
        if (idx < 5376) {                       // 48 rows * 112 ch-pairs
            int r  = (idx * 18725) >> 21;       // idx/112
            int cp = idx - r*112;
            int c0 = cp*2;
            int grow = mi*48 + r;
            int h  = (grow * 171) >> 11;        // grow/12
            int wv = grow - h*12;
            float v0, v1;
            if (c0 < 196) {
                int n1a = (c0 * 293) >> 12, n2a = c0 - 14*n1a;
                int c1 = c0 + 1;
                int n1b = (c1 * 293) >> 12, n2b = c1 - 14*n1b;
                float xi0 = xns[n1a*12 + h], xj0 = xns[n2a*12 + wv];
                v0 = (xj0 - xi0) * __builtin_amdgcn_rcpf(xi0 + xj0 + 1e-5f);
                float xi1 = xns[n1b*12 + h], xj1 = xns[n2b*12 + wv];
                v1 = (xj1 - xi1) * __builtin_amdgcn_rcpf(xi1 + xj1 + 1e-5f);
            } else {
                v0 = (c0 < 210) ? xns[(c0-196)*12 + wv] : xns[(c0-210)*12 + h];
                int c1 = c0 + 1;
                v1 = (c1 < 210) ? xns[(c1-196)*12 + wv] : xns[(c1-210)*12 + h];
            }
            *(uint_t*)(smem + OFF_FEAT + ((r*512 + c0*2) ^ ((r & 7) << 4))) = pack_bf16(v0, v1);
        }
    }
    __syncthreads();   // feat ready

    const int NT1 = w * 3;
    const int NT2 = w * 2;

    // ====== Layer 0: K=224 (7 kt), TWO nt-passes of 2 (acc = 24 AGPR, not 48) ======
    {
        const float* bias0p = wsf + WS_B0P_F;
        #pragma unroll 1
        for (int p = 0; p < 2; ++p) {
            const int NP = w*4 + p*2;
            f32x4 acc[3][2];
            #pragma unroll
            for (int m = 0; m < 3; ++m)
                #pragma unroll
                for (int nt = 0; nt < 2; ++nt) acc[m][nt] = (f32x4){0.f,0.f,0.f,0.f};

            bhalf8 BA[2], BB[2];
            #define LOADB0(dst, ktv) { _Pragma("unroll") \
                for (int nt = 0; nt < 2; ++nt) \
                    dst[nt] = *(const bhalf8*)(w0p + (ktv)*16384 + ((NP+nt)*16+col)*32 + r4*8); }
            #define PHASE0(B, ktv) { _Pragma("unroll") \
                for (int m = 0; m < 3; ++m) { \
                    int row = m*16 + col; \
                    bhalf8 a = *(const bhalf8*)(smem + OFF_FEAT + ((row*512 + (ktv)*64 + r4*16) ^ swzA)); \
                    _Pragma("unroll") \
                    for (int nt = 0; nt < 2; ++nt) \
                        acc[m][nt] = __builtin_amdgcn_mfma_f32_16x16x32_bf16(a, B[nt], acc[m][nt], 0, 0, 0); } }

            LOADB0(BA, 0);
            for (int ktb = 0; ktb < 3; ++ktb) {
                int kt = 2*ktb;
                LOADB0(BB, kt+1);
                PHASE0(BA, kt);
                LOADB0(BA, kt+2);        // kt+2 <= 6, always valid
                PHASE0(BB, kt+1);
            }
            PHASE0(BA, 6);
            // h0 epilogue for this pass's 2 cols (feat untouched: separate region)
            float bb[2];
            #pragma unroll
            for (int nt = 0; nt < 2; ++nt) bb[nt] = bias0p[(NP+nt)*16 + col];
            #pragma unroll
            for (int m = 0; m < 3; ++m)
                #pragma unroll
                for (int nt = 0; nt < 2; ++nt) {
                    int o = (NP+nt)*16 + col;
                    #pragma unroll
                    for (int qp = 0; qp < 2; ++qp) {
                        float v0 = fmaxf(acc[m][nt][2*qp]   + bb[nt], 0.f);
                        float v1 = fmaxf(acc[m][nt][2*qp+1] + bb[nt], 0.f);
                        uint_t pk = pack_bf16(v0, v1);
                        int row0 = m*16 + r4*4 + 2*qp;
                        *(ushort_t*)(smem + ((row0*1024 + o*2) ^ ((row0 & 7) << 4))) = (ushort_t)pk;
                        int row1 = row0 + 1;
                        *(ushort_t*)(smem + ((row1*1024 + o*2) ^ ((row1 & 7) << 4))) = (ushort_t)(pk >> 16);
                    }
                }
        }
    }
    __syncthreads();   // h0 ready

    // ================= Layer 1: 512 -> 384 (16 kt), no barriers in loop =================
    {
        f32x4 acc1[3][3];
        #pragma unroll
        for (int m = 0; m < 3; ++m)
            #pragma unroll
            for (int nt = 0; nt < 3; ++nt) acc1[m][nt] = (f32x4){0.f,0.f,0.f,0.f};

        bhalf8 BA[3], BB[3];
        #define LOADB1(dst, ktv) { _Pragma("unroll") \
            for (int nt = 0; nt < 3; ++nt) \
                dst[nt] = *(const bhalf8*)(w1p + (ktv)*12288 + ((NT1+nt)*16+col)*32 + r4*8); }
        #define PHASE1(B, ktv) { _Pragma("unroll") \
            for (int m = 0; m < 3; ++m) { \
                int row = m*16 + col; \
                bhalf8 a = *(const bhalf8*)(smem + ((row*1024 + (ktv)*64 + r4*16) ^ swzA)); \
                _Pragma("unroll") \
                for (int nt = 0; nt < 3; ++nt) \
                    acc1[m][nt] = __builtin_amdgcn_mfma_f32_16x16x32_bf16(a, B[nt], acc1[m][nt], 0, 0, 0); } }

        LOADB1(BA, 0);
        for (int ktb = 0; ktb < 8; ++ktb) {
            int kt = 2*ktb;
            LOADB1(BB, kt+1);
            PHASE1(BA, kt);
            if (kt+2 < 16) LOADB1(BA, kt+2);
            PHASE1(BB, kt+1);
        }
        __syncthreads();   // all h0 reads done before h1 overwrite
        float bb[3];
        #pragma unroll
        for (int nt = 0; nt < 3; ++nt) bb[nt] = b1[(NT1+nt)*16 + col];
        #pragma unroll
        for (int m = 0; m < 3; ++m)
            #pragma unroll
            for (int nt = 0; nt < 3; ++nt) {
                int o = (NT1+nt)*16 + col;
                #pragma unroll
                for (int qp = 0; qp < 2; ++qp) {
                    float v0 = fmaxf(acc1[m][nt][2*qp]   + bb[nt], 0.f);
                    float v1 = fmaxf(acc1[m][nt][2*qp+1] + bb[nt], 0.f);
                    uint_t pk = pack_bf16(v0, v1);
                    int row0 = m*16 + r4*4 + 2*qp;
                    *(ushort_t*)(smem + ((row0*768 + o*2) ^ ((row0 & 7) << 4))) = (ushort_t)pk;
                    int row1 = row0 + 1;
                    *(ushort_t*)(smem + ((row1*768 + o*2) ^ ((row1 & 7) << 4))) = (ushort_t)(pk >> 16);
                }
            }
    }
    __syncthreads();   // h1 ready

    // ================= Layer 2: 384 -> 256 (12 kt) + pool partial =================
    {
        f32x4 acc2[3][2];
        #pragma unroll
        for (int m = 0; m < 3; ++m)
            #pragma unroll
            for (int nt = 0; nt < 2; ++nt) acc2[m][nt] = (f32x4){0.f,0.f,0.f,0.f};

        bhalf8 BA[2], BB[2];
        #define LOADB2(dst, ktv) { _Pragma("unroll") \
            for (int nt = 0; nt < 2; ++nt) \
                dst[nt] = *(const bhalf8*)(w2p + (ktv)*8192 + ((NT2+nt)*16+col)*32 + r4*8); }
        #define PHASE2(B, ktv) { _Pragma("unroll") \
            for (int m = 0; m < 3; ++m) { \
                int row = m*16 + col; \
                bhalf8 a = *(const bhalf8*)(smem + ((row*768 + (ktv)*64 + r4*16) ^ swzA)); \
                _Pragma("unroll") \
                for (int nt = 0; nt < 2; ++nt) \
                    acc2[m][nt] = __builtin_amdgcn_mfma_f32_16x16x32_bf16(a, B[nt], acc2[m][nt], 0, 0, 0); } }

        LOADB2(BA, 0);
        for (int ktb = 0; ktb < 6; ++ktb) {
            int kt = 2*ktb;
            LOADB2(BB, kt+1);
            PHASE2(BA, kt);
            if (kt+2 < 12) LOADB2(BA, kt+2);
            PHASE2(BB, kt+1);
        }
        const float* maskG = wsf + WS_MASK_F;
        float bb[2];
        #pragma unroll
        for (int nt = 0; nt < 2; ++nt) bb[nt] = b2[(NT2+nt)*16 + col];
        float pooled[2] = {0.f, 0.f};
        #pragma unroll
        for (int nt = 0; nt < 2; ++nt) {
            int g = NT2 + nt;
            #pragma unroll
            for (int m = 0; m < 3; ++m) {
                int p0 = mi*48 + m*16 + r4*4;
                float4 mv = *(const float4*)(maskG + g*144 + p0);
                pooled[nt] += mv.x * fmaxf(acc2[m][nt][0] + bb[nt], 0.f);
                pooled[nt] += mv.y * fmaxf(acc2[m][nt][1] + bb[nt], 0.f);
                pooled[nt] += mv.z * fmaxf(acc2[m][nt][2] + bb[nt], 0.f);
                pooled[nt] += mv.w * fmaxf(acc2[m][nt][3] + bb[nt], 0.f);
            }
        }
        #pragma unroll
        for (int nt = 0; nt < 2; ++nt) {
            pooled[nt] += __shfl_xor(pooled[nt], 16);
            pooled[nt] += __shfl_xor(pooled[nt], 32);
            if (r4 == 0) atomicAdd(&out[b*256 + (NT2+nt)*16 + col], pooled[nt]);
        }
    }
}

extern "C" void kernel_launch(void* const* d_in, const int* in_sizes, int n_in,
                              void* d_out, int out_size, void* d_ws, size_t ws_size,
                              hipStream_t stream) {
    const float* x  = (const float*)d_in[0];
    const float* w0 = (const float*)d_in[1];
    const float* b0 = (const float*)d_in[2];
    const float* w1 = (const float*)d_in[3];
    const float* b1 = (const float*)d_in[4];
    const float* w2 = (const float*)d_in[5];
    const float* b2 = (const float*)d_in[6];
    const float* wm = (const float*)d_in[7];
    float* out = (float*)d_out;
    float* wsf = (float*)d_ws;
    ushort_t* w0p = (ushort_t*)((char*)d_ws + OFF_W0P);
    ushort_t* w1p = (ushort_t*)((char*)d_ws + OFF_W1P);
    ushort_t* w2p = (ushort_t*)((char*)d_ws + OFF_W2P);

    hipMemsetAsync(d_ws, 0, 8, stream);
    hipMemsetAsync(d_out, 0, (size_t)out_size * sizeof(float), stream);
    stats_kernel<<<256, 256, 0, stream>>>(x, wsf);
    prep_bf16<<<512, 256, 0, stream>>>(w0, b0, w1, w2, wsf, w0p, w1p, w2p);
    mask_kernel<<<16, 256, 0, stream>>>(wm, wsf);
    fused_mfma<<<3*2048, 512, 0, stream>>>(x, b1, b2, wsf, w0p, w1p, w2p, out);
}